// Round 4
// baseline (885.475 us; speedup 1.0000x reference)
//
#include <hip/hip_runtime.h>
#include <hip/hip_bf16.h>
#include <stdint.h>

#define T_   8192   // B*S tokens
#define IN_  4096
#define OUT_ 4096
#define GS_  256
#define NG_  16

#define BM 128
#define BN 128
#define BK 128
#define KT (IN_ / BK)   // 32 K-tiles, group = 2 K-tiles

typedef int   v4i __attribute__((ext_vector_type(4)));
typedef float f4  __attribute__((ext_vector_type(4)));

__device__ __forceinline__ void gload16(const void* g, void* l) {
  __builtin_amdgcn_global_load_lds(
      (const __attribute__((address_space(1))) void*)g,
      (__attribute__((address_space(3))) void*)l, 16, 0, 0);
}

// ---------------- per-token dynamic quant ----------------------------------
// Exact divides only for scale/zp; per-element uses x*(1/scale) (rintf slack
// absorbed by the 0.615 absmax threshold; one LSB of q ~ 0.01 in the output).
__global__ __launch_bounds__(256) void quant_kernel(
    const float* __restrict__ x, int8_t* __restrict__ q,
    float* __restrict__ tscale, float* __restrict__ tzp) {
  const int t = blockIdx.x;
  const int tid = threadIdx.x;
  const float* xr = x + (size_t)t * IN_ + tid * 16;
  float vals[16];
  {
    f4 v0 = *(const f4*)(xr);
    f4 v1 = *(const f4*)(xr + 4);
    f4 v2 = *(const f4*)(xr + 8);
    f4 v3 = *(const f4*)(xr + 12);
#pragma unroll
    for (int i = 0; i < 4; ++i) {
      vals[i] = v0[i]; vals[4 + i] = v1[i]; vals[8 + i] = v2[i]; vals[12 + i] = v3[i];
    }
  }
  float mn = 0.f, mx = 0.f;   // ref clamps: min(.,0), max(.,0)
#pragma unroll
  for (int i = 0; i < 16; ++i) { mn = fminf(mn, vals[i]); mx = fmaxf(mx, vals[i]); }
#pragma unroll
  for (int off = 32; off > 0; off >>= 1) {
    mn = fminf(mn, __shfl_xor(mn, off));
    mx = fmaxf(mx, __shfl_xor(mx, off));
  }
  __shared__ float smn[4], smx[4];
  if ((tid & 63) == 0) { smn[tid >> 6] = mn; smx[tid >> 6] = mx; }
  __syncthreads();
  mn = fminf(fminf(smn[0], smn[1]), fminf(smn[2], smn[3]));
  mx = fmaxf(fmaxf(smx[0], smx[1]), fmaxf(smx[2], smx[3]));

  const float eps = 1.1920928955078125e-7f;  // np.finfo(float32).eps
  float scale = fmaxf((mx - mn) / 255.0f, eps);
  float rmn = mn / scale;   // exact divide (zp must be bit-exact)
  float rmx = mx / scale;
  float zp0 = ((-128.0f + rmn) + (127.0f + rmx) > 0.0f) ? (-128.0f - rmn)
                                                        : (127.0f - rmx);
  float zp = fminf(fmaxf(rintf(zp0), -128.0f), 127.0f);
  if (tid == 0) { tscale[t] = scale; tzp[t] = zp; }

  const float inv = 1.0f / scale;  // one exact divide; 16 multiplies below
  v4i packed;
#pragma unroll
  for (int w = 0; w < 4; ++w) {
    int word = 0;
#pragma unroll
    for (int e = 0; e < 4; ++e) {
      float qf = rintf(vals[w * 4 + e] * inv) + zp;
      qf = fminf(fmaxf(qf, -128.0f), 127.0f);
      int qi = (int)qf;
      word |= (qi & 0xff) << (8 * e);
    }
    packed[w] = word;
  }
  *(v4i*)(q + (size_t)t * IN_ + tid * 16) = packed;
}

// ---------------- weight prep: w' = w - z (int8), C1[o] = sum_g s*sum(w') ---
__global__ __launch_bounds__(256) void wprep_kernel(
    const int* __restrict__ w, const float* __restrict__ scales,
    const float* __restrict__ zeros, int8_t* __restrict__ wq,
    float* __restrict__ c1) {
  const int o = blockIdx.x;
  const int tid = threadIdx.x;
  const int g = tid >> 4;  // 16 threads per group of 256 elems
  const int* wr = w + (size_t)o * IN_ + tid * 16;
  const int zi = (int)zeros[o * NG_ + g];
  int ssum = 0;
  v4i packed;
#pragma unroll
  for (int blk = 0; blk < 4; ++blk) {
    v4i ww = *(const v4i*)(wr + blk * 4);
    int word = 0;
#pragma unroll
    for (int e = 0; e < 4; ++e) {
      int wp = ww[e] - zi;   // in [-15,15], fits int8
      ssum += wp;
      word |= (wp & 0xff) << (8 * e);
    }
    packed[blk] = word;
  }
  *(v4i*)(wq + (size_t)o * IN_ + tid * 16) = packed;
  ssum += __shfl_xor(ssum, 1);
  ssum += __shfl_xor(ssum, 2);
  ssum += __shfl_xor(ssum, 4);
  ssum += __shfl_xor(ssum, 8);
  __shared__ float part[NG_];
  if ((tid & 15) == 0) part[g] = scales[o * NG_ + g] * (float)ssum;
  __syncthreads();
  if (tid == 0) {
    float s = 0.f;
#pragma unroll
    for (int i = 0; i < NG_; ++i) s += part[i];
    c1[o] = s;
  }
}

// ---------------- int8 groupwise GEMM: A via LDS, B direct from L2 ----------
// Round-3 post-mortem: LDS port saturated (frag reads 64 KB/kt/block at
// 85 B/cy = ~2050 LDS-cy per 1855-cy kt-slot with 2 blocks).  Fix: take B out
// of LDS entirely.  B fragments are plain contiguous 16-B chunks of wq rows
// (wq[C0+wn+16j+lm][kt*128+ks*64+quad*16]) -> load straight to registers.
// wq is 16.7 MB (L3-resident); per-XCD working set ~2.5 MB < 4 MB L2 with
// natural x-major dispatch, so these hit L2/L3, a previously idle pipe.
// LDS traffic halves (reads 4.3->2.1 GB), LDS/block drops 72->40 KB ->
// 4 blocks/CU (16 waves) of TLP to hide L2 latency and barrier drains.
// A path unchanged from the verified kernel: XOR-chunk swizzled layout,
// double-buffered, prefetch-at-top, one __syncthreads per kt.
__global__ __launch_bounds__(256, 4) void gemm_kernel(
    const int8_t* __restrict__ q, const int8_t* __restrict__ wq,
    const float* __restrict__ scales, const float* __restrict__ tscale,
    const float* __restrict__ tzp, const float* __restrict__ c1,
    float* __restrict__ out) {
  __shared__ int8_t As[2][BM * BK];   // 2 x 16 KB
  __shared__ float sSc[NG_ * BN];     // 8 KB   (40 KB total -> 4 blocks/CU)

  const int tid = threadIdx.x;
  const int lane = tid & 63;
  const int wid = tid >> 6;
  const int R0 = blockIdx.y * BM;
  const int C0 = blockIdx.x * BN;

  // stage this block's scales: sSc[g][col_local]
#pragma unroll
  for (int e = 0; e < 8; ++e) {
    int idx = tid + e * 256;
    int oc = idx >> 4, g = idx & 15;
    sSc[g * BN + oc] = scales[(size_t)(C0 + oc) * NG_ + g];
  }

  // A staging: thread covers 16 B; row = tid>>3 (+32 per i), phys chunk tid&7
  const int rA = tid >> 3;                       // 0..31
  const int cswz = ((tid & 7) ^ (rA & 7)) * 16;  // swizzled global column
  const int8_t* gA = q + (size_t)(R0 + rA) * IN_ + cswz;

  const int wm = (wid >> 1) * 64;
  const int wn = (wid & 1) * 64;
  const int lm = lane & 15;
  const int quad = lane >> 4;
  // A fragment read offsets: logical chunk (ks*4+quad) ^ (lm&7)
  const int o0 = ((quad ^ (lm & 7)) * 16);       // ks=0
  const int aRow = (wm + lm) * BK;

  // B fragment base: row C0+wn+lm (+16j), k-bytes kt*128 + ks*64 + quad*16
  const int8_t* bBase = wq + (size_t)(C0 + wn + lm) * IN_ + quad * 16;

  v4i acci[4][4];
  float accf[4][4][4];
#pragma unroll
  for (int i = 0; i < 4; ++i)
#pragma unroll
    for (int j = 0; j < 4; ++j) {
      acci[i][j] = (v4i){0, 0, 0, 0};
#pragma unroll
      for (int r = 0; r < 4; ++r) accf[i][j][r] = 0.f;
    }

  // prologue: stage A tile 0 into buffer 0
#pragma unroll
  for (int i = 0; i < 4; ++i)
    gload16(gA + (size_t)(i * 32) * IN_, &As[0][i * 4096 + tid * 16]);
  __syncthreads();   // drains vmcnt (tile 0 resident); also covers sSc writes

  int cur = 0;
  for (int kt = 0; kt < KT; ++kt) {
    // prefetch A tile kt+1 into the other buffer (drained by end-of-kt sync)
    if (kt + 1 < KT) {
      const size_t koff = (size_t)(kt + 1) * BK;
#pragma unroll
      for (int i = 0; i < 4; ++i)
        gload16(gA + koff + (size_t)(i * 32) * IN_,
                &As[cur ^ 1][i * 4096 + tid * 16]);
    }

    // B fragments for this kt straight from global (L2-resident panel)
    const int8_t* bk = bBase + (size_t)kt * BK;
    v4i bf0[4], bf1[4];
#pragma unroll
    for (int j = 0; j < 4; ++j) {
      bf0[j] = *(const v4i*)(bk + (size_t)j * (16 * IN_));
      bf1[j] = *(const v4i*)(bk + (size_t)j * (16 * IN_) + 64);
    }

    {  // ks = 0
      v4i af[4];
#pragma unroll
      for (int i = 0; i < 4; ++i)
        af[i] = *(const v4i*)&As[cur][aRow + i * (16 * BK) + o0];
#pragma unroll
      for (int i = 0; i < 4; ++i)
#pragma unroll
        for (int j = 0; j < 4; ++j)
          acci[i][j] =
              __builtin_amdgcn_mfma_i32_16x16x64_i8(af[i], bf0[j], acci[i][j], 0, 0, 0);
    }
    {  // ks = 1
      const int co = o0 ^ 64;
      v4i af[4];
#pragma unroll
      for (int i = 0; i < 4; ++i)
        af[i] = *(const v4i*)&As[cur][aRow + i * (16 * BK) + co];
#pragma unroll
      for (int i = 0; i < 4; ++i)
#pragma unroll
        for (int j = 0; j < 4; ++j)
          acci[i][j] =
              __builtin_amdgcn_mfma_i32_16x16x64_i8(af[i], bf1[j], acci[i][j], 0, 0, 0);
    }

    if (kt & 1) {  // group boundary (group = 2 kt): fold int acc into fp32
      const int g = kt >> 1;
      float sj[4];
#pragma unroll
      for (int j = 0; j < 4; ++j) sj[j] = sSc[g * BN + wn + j * 16 + lm];
#pragma unroll
      for (int i = 0; i < 4; ++i)
#pragma unroll
        for (int j = 0; j < 4; ++j) {
#pragma unroll
          for (int r = 0; r < 4; ++r)
            accf[i][j][r] += sj[j] * (float)acci[i][j][r];
          acci[i][j] = (v4i){0, 0, 0, 0};
        }
    }

    __syncthreads();  // vmcnt(0)+barrier: A(kt+1) resident, As[cur] reads done
    cur ^= 1;
  }

  // epilogue: out = scale_t * (accf - zp_t * C1[o])
  float cj[4];
#pragma unroll
  for (int j = 0; j < 4; ++j) cj[j] = c1[C0 + wn + j * 16 + lm];
#pragma unroll
  for (int i = 0; i < 4; ++i) {
#pragma unroll
    for (int r = 0; r < 4; ++r) {
      const int row = R0 + wm + i * 16 + quad * 4 + r;
      const float tsc = tscale[row];
      const float tz = tzp[row];
#pragma unroll
      for (int j = 0; j < 4; ++j) {
        const int col = C0 + wn + j * 16 + lm;
        out[(size_t)row * OUT_ + col] = tsc * (accf[i][j][r] - tz * cj[j]);
      }
    }
  }
}

extern "C" void kernel_launch(void* const* d_in, const int* in_sizes, int n_in,
                              void* d_out, int out_size, void* d_ws, size_t ws_size,
                              hipStream_t stream) {
  const float* x = (const float*)d_in[0];
  const int* w = (const int*)d_in[1];       // int inputs materialized as int32
  const float* scales = (const float*)d_in[2];
  const float* zeros = (const float*)d_in[3];
  // d_in[4] = group_size scalar (256), baked in at compile time

  uint8_t* ws = (uint8_t*)d_ws;
  int8_t* q = (int8_t*)ws;                                  // 33,554,432 B
  int8_t* wq = (int8_t*)(ws + 33554432);                    // 16,777,216 B
  float* tscale = (float*)(ws + 33554432 + 16777216);       // 32 KB
  float* tzp = (float*)(ws + 33554432 + 16777216 + 32768);  // 32 KB
  float* c1 = (float*)(ws + 33554432 + 16777216 + 65536);   // 16 KB
  float* out = (float*)d_out;

  hipLaunchKernelGGL(quant_kernel, dim3(T_), dim3(256), 0, stream, x, q, tscale, tzp);
  hipLaunchKernelGGL(wprep_kernel, dim3(OUT_), dim3(256), 0, stream, w, scales, zeros, wq, c1);
  hipLaunchKernelGGL(gemm_kernel, dim3(OUT_ / BN, T_ / BM), dim3(256), 0, stream,
                     q, wq, scales, tscale, tzp, c1, out);
}

// Round 5
// 761.670 us; speedup vs baseline: 1.1625x; 1.1625x over previous
//
#include <hip/hip_runtime.h>
#include <hip/hip_bf16.h>
#include <stdint.h>

#define T_   8192   // B*S tokens
#define IN_  4096
#define OUT_ 4096
#define GS_  256
#define NG_  16

#define BM 128
#define BN 128
#define BK 128
#define KT (IN_ / BK)   // 32 K-tiles, group = 2 K-tiles

typedef int   v4i __attribute__((ext_vector_type(4)));
typedef float f4  __attribute__((ext_vector_type(4)));

__device__ __forceinline__ void gload16(const void* g, void* l) {
  __builtin_amdgcn_global_load_lds(
      (const __attribute__((address_space(1))) void*)g,
      (__attribute__((address_space(3))) void*)l, 16, 0, 0);
}

// ---------------- per-token dynamic quant ----------------------------------
// Exact divides only for scale/zp; per-element uses x*(1/scale) (rintf slack
// absorbed by the 0.615 absmax threshold; one LSB of q ~ 0.01 in the output).
__global__ __launch_bounds__(256) void quant_kernel(
    const float* __restrict__ x, int8_t* __restrict__ q,
    float* __restrict__ tscale, float* __restrict__ tzp) {
  const int t = blockIdx.x;
  const int tid = threadIdx.x;
  const float* xr = x + (size_t)t * IN_ + tid * 16;
  float vals[16];
  {
    f4 v0 = *(const f4*)(xr);
    f4 v1 = *(const f4*)(xr + 4);
    f4 v2 = *(const f4*)(xr + 8);
    f4 v3 = *(const f4*)(xr + 12);
#pragma unroll
    for (int i = 0; i < 4; ++i) {
      vals[i] = v0[i]; vals[4 + i] = v1[i]; vals[8 + i] = v2[i]; vals[12 + i] = v3[i];
    }
  }
  float mn = 0.f, mx = 0.f;   // ref clamps: min(.,0), max(.,0)
#pragma unroll
  for (int i = 0; i < 16; ++i) { mn = fminf(mn, vals[i]); mx = fmaxf(mx, vals[i]); }
#pragma unroll
  for (int off = 32; off > 0; off >>= 1) {
    mn = fminf(mn, __shfl_xor(mn, off));
    mx = fmaxf(mx, __shfl_xor(mx, off));
  }
  __shared__ float smn[4], smx[4];
  if ((tid & 63) == 0) { smn[tid >> 6] = mn; smx[tid >> 6] = mx; }
  __syncthreads();
  mn = fminf(fminf(smn[0], smn[1]), fminf(smn[2], smn[3]));
  mx = fmaxf(fmaxf(smx[0], smx[1]), fmaxf(smx[2], smx[3]));

  const float eps = 1.1920928955078125e-7f;  // np.finfo(float32).eps
  float scale = fmaxf((mx - mn) / 255.0f, eps);
  float rmn = mn / scale;   // exact divide (zp must be bit-exact)
  float rmx = mx / scale;
  float zp0 = ((-128.0f + rmn) + (127.0f + rmx) > 0.0f) ? (-128.0f - rmn)
                                                        : (127.0f - rmx);
  float zp = fminf(fmaxf(rintf(zp0), -128.0f), 127.0f);
  if (tid == 0) { tscale[t] = scale; tzp[t] = zp; }

  const float inv = 1.0f / scale;  // one exact divide; 16 multiplies below
  v4i packed;
#pragma unroll
  for (int w = 0; w < 4; ++w) {
    int word = 0;
#pragma unroll
    for (int e = 0; e < 4; ++e) {
      float qf = rintf(vals[w * 4 + e] * inv) + zp;
      qf = fminf(fmaxf(qf, -128.0f), 127.0f);
      int qi = (int)qf;
      word |= (qi & 0xff) << (8 * e);
    }
    packed[w] = word;
  }
  *(v4i*)(q + (size_t)t * IN_ + tid * 16) = packed;
}

// ---------------- weight prep: w' = w - z (int8), C1[o] = sum_g s*sum(w') ---
__global__ __launch_bounds__(256) void wprep_kernel(
    const int* __restrict__ w, const float* __restrict__ scales,
    const float* __restrict__ zeros, int8_t* __restrict__ wq,
    float* __restrict__ c1) {
  const int o = blockIdx.x;
  const int tid = threadIdx.x;
  const int g = tid >> 4;  // 16 threads per group of 256 elems
  const int* wr = w + (size_t)o * IN_ + tid * 16;
  const int zi = (int)zeros[o * NG_ + g];
  int ssum = 0;
  v4i packed;
#pragma unroll
  for (int blk = 0; blk < 4; ++blk) {
    v4i ww = *(const v4i*)(wr + blk * 4);
    int word = 0;
#pragma unroll
    for (int e = 0; e < 4; ++e) {
      int wp = ww[e] - zi;   // in [-15,15], fits int8
      ssum += wp;
      word |= (wp & 0xff) << (8 * e);
    }
    packed[blk] = word;
  }
  *(v4i*)(wq + (size_t)o * IN_ + tid * 16) = packed;
  ssum += __shfl_xor(ssum, 1);
  ssum += __shfl_xor(ssum, 2);
  ssum += __shfl_xor(ssum, 4);
  ssum += __shfl_xor(ssum, 8);
  __shared__ float part[NG_];
  if ((tid & 15) == 0) part[g] = scales[o * NG_ + g] * (float)ssum;
  __syncthreads();
  if (tid == 0) {
    float s = 0.f;
#pragma unroll
    for (int i = 0; i < NG_; ++i) s += part[i];
    c1[o] = s;
  }
}

// ---------------- int8 groupwise GEMM: A via LDS, B direct from L2 ----------
// Round-4 post-mortem: the structure was right but __launch_bounds__(256,4)
// capped VGPR at 128 < the ~200 this kernel needs -> accumulator spill
// (WRITE_SIZE 1.6 GB).  This round: identical kernel, allocator freed
// (__launch_bounds__(256) only).  Expected ~200 VGPR -> 2 blocks/CU, same
// occupancy as the 197-us baseline but with HALF the LDS traffic:
//   LDS: A reads 2.1 GB + writes 1.07 GB  (~55 us pipe, below 70 us MFMA)
//   L2:  B reads 2.1 GB (~61 us at 34.5 TB/s, previously idle pipe)
// B fragments are contiguous 16-B chunks of wq rows
// (wq[C0+wn+16j+lm][kt*128+ks*64+quad*16]) -> plain global_load_dwordx4,
// issued FIRST each iteration (no dependencies) so L2 latency is covered by
// the A ds_reads + co-resident block.  wq = 16.7 MB, L3-resident; per row the
// four quads cover one full 64-B line (no over-fetch).
// A path byte-identical to the verified kernel: XOR-chunk swizzled layout,
// double-buffered, prefetch-at-top, one __syncthreads per kt.
__global__ __launch_bounds__(256) void gemm_kernel(
    const int8_t* __restrict__ q, const int8_t* __restrict__ wq,
    const float* __restrict__ scales, const float* __restrict__ tscale,
    const float* __restrict__ tzp, const float* __restrict__ c1,
    float* __restrict__ out) {
  __shared__ int8_t As[2][BM * BK];   // 2 x 16 KB
  __shared__ float sSc[NG_ * BN];     // 8 KB   (40 KB total)

  const int tid = threadIdx.x;
  const int lane = tid & 63;
  const int wid = tid >> 6;
  const int R0 = blockIdx.y * BM;
  const int C0 = blockIdx.x * BN;

  // stage this block's scales: sSc[g][col_local]
#pragma unroll
  for (int e = 0; e < 8; ++e) {
    int idx = tid + e * 256;
    int oc = idx >> 4, g = idx & 15;
    sSc[g * BN + oc] = scales[(size_t)(C0 + oc) * NG_ + g];
  }

  // A staging: thread covers 16 B; row = tid>>3 (+32 per i), phys chunk tid&7
  const int rA = tid >> 3;                       // 0..31
  const int cswz = ((tid & 7) ^ (rA & 7)) * 16;  // swizzled global column
  const int8_t* gA = q + (size_t)(R0 + rA) * IN_ + cswz;

  const int wm = (wid >> 1) * 64;
  const int wn = (wid & 1) * 64;
  const int lm = lane & 15;
  const int quad = lane >> 4;
  // A fragment read offsets: logical chunk (ks*4+quad) ^ (lm&7)
  const int o0 = ((quad ^ (lm & 7)) * 16);       // ks=0
  const int aRow = (wm + lm) * BK;

  // B fragment base: row C0+wn+lm (+16j), k-bytes kt*128 + ks*64 + quad*16
  const int8_t* bBase = wq + (size_t)(C0 + wn + lm) * IN_ + quad * 16;

  v4i acci[4][4];
  float accf[4][4][4];
#pragma unroll
  for (int i = 0; i < 4; ++i)
#pragma unroll
    for (int j = 0; j < 4; ++j) {
      acci[i][j] = (v4i){0, 0, 0, 0};
#pragma unroll
      for (int r = 0; r < 4; ++r) accf[i][j][r] = 0.f;
    }

  // prologue: stage A tile 0 into buffer 0
#pragma unroll
  for (int i = 0; i < 4; ++i)
    gload16(gA + (size_t)(i * 32) * IN_, &As[0][i * 4096 + tid * 16]);
  __syncthreads();   // drains vmcnt (tile 0 resident); also covers sSc writes

  int cur = 0;
  for (int kt = 0; kt < KT; ++kt) {
    // B fragments for this kt straight from global (L2/L3-resident panel);
    // issued first: no dependencies, latency hidden under ds_reads below
    const int8_t* bk = bBase + (size_t)kt * BK;
    v4i bf0[4], bf1[4];
#pragma unroll
    for (int j = 0; j < 4; ++j) {
      bf0[j] = *(const v4i*)(bk + (size_t)j * (16 * IN_));
      bf1[j] = *(const v4i*)(bk + (size_t)j * (16 * IN_) + 64);
    }

    // prefetch A tile kt+1 into the other buffer (drained by end-of-kt sync)
    if (kt + 1 < KT) {
      const size_t koff = (size_t)(kt + 1) * BK;
#pragma unroll
      for (int i = 0; i < 4; ++i)
        gload16(gA + koff + (size_t)(i * 32) * IN_,
                &As[cur ^ 1][i * 4096 + tid * 16]);
    }

    {  // ks = 0
      v4i af[4];
#pragma unroll
      for (int i = 0; i < 4; ++i)
        af[i] = *(const v4i*)&As[cur][aRow + i * (16 * BK) + o0];
#pragma unroll
      for (int i = 0; i < 4; ++i)
#pragma unroll
        for (int j = 0; j < 4; ++j)
          acci[i][j] =
              __builtin_amdgcn_mfma_i32_16x16x64_i8(af[i], bf0[j], acci[i][j], 0, 0, 0);
    }
    {  // ks = 1
      const int co = o0 ^ 64;
      v4i af[4];
#pragma unroll
      for (int i = 0; i < 4; ++i)
        af[i] = *(const v4i*)&As[cur][aRow + i * (16 * BK) + co];
#pragma unroll
      for (int i = 0; i < 4; ++i)
#pragma unroll
        for (int j = 0; j < 4; ++j)
          acci[i][j] =
              __builtin_amdgcn_mfma_i32_16x16x64_i8(af[i], bf1[j], acci[i][j], 0, 0, 0);
    }

    if (kt & 1) {  // group boundary (group = 2 kt): fold int acc into fp32
      const int g = kt >> 1;
      float sj[4];
#pragma unroll
      for (int j = 0; j < 4; ++j) sj[j] = sSc[g * BN + wn + j * 16 + lm];
#pragma unroll
      for (int i = 0; i < 4; ++i)
#pragma unroll
        for (int j = 0; j < 4; ++j) {
#pragma unroll
          for (int r = 0; r < 4; ++r)
            accf[i][j][r] += sj[j] * (float)acci[i][j][r];
          acci[i][j] = (v4i){0, 0, 0, 0};
        }
    }

    __syncthreads();  // vmcnt(0)+barrier: A(kt+1) resident, As[cur] reads done
    cur ^= 1;
  }

  // epilogue: out = scale_t * (accf - zp_t * C1[o])
  float cj[4];
#pragma unroll
  for (int j = 0; j < 4; ++j) cj[j] = c1[C0 + wn + j * 16 + lm];
#pragma unroll
  for (int i = 0; i < 4; ++i) {
#pragma unroll
    for (int r = 0; r < 4; ++r) {
      const int row = R0 + wm + i * 16 + quad * 4 + r;
      const float tsc = tscale[row];
      const float tz = tzp[row];
#pragma unroll
      for (int j = 0; j < 4; ++j) {
        const int col = C0 + wn + j * 16 + lm;
        out[(size_t)row * OUT_ + col] = tsc * (accf[i][j][r] - tz * cj[j]);
      }
    }
  }
}

extern "C" void kernel_launch(void* const* d_in, const int* in_sizes, int n_in,
                              void* d_out, int out_size, void* d_ws, size_t ws_size,
                              hipStream_t stream) {
  const float* x = (const float*)d_in[0];
  const int* w = (const int*)d_in[1];       // int inputs materialized as int32
  const float* scales = (const float*)d_in[2];
  const float* zeros = (const float*)d_in[3];
  // d_in[4] = group_size scalar (256), baked in at compile time

  uint8_t* ws = (uint8_t*)d_ws;
  int8_t* q = (int8_t*)ws;                                  // 33,554,432 B
  int8_t* wq = (int8_t*)(ws + 33554432);                    // 16,777,216 B
  float* tscale = (float*)(ws + 33554432 + 16777216);       // 32 KB
  float* tzp = (float*)(ws + 33554432 + 16777216 + 32768);  // 32 KB
  float* c1 = (float*)(ws + 33554432 + 16777216 + 65536);   // 16 KB
  float* out = (float*)d_out;

  hipLaunchKernelGGL(quant_kernel, dim3(T_), dim3(256), 0, stream, x, q, tscale, tzp);
  hipLaunchKernelGGL(wprep_kernel, dim3(OUT_), dim3(256), 0, stream, w, scales, zeros, wq, c1);
  hipLaunchKernelGGL(gemm_kernel, dim3(OUT_ / BN, T_ / BM), dim3(256), 0, stream,
                     q, wq, scales, tscale, tzp, c1, out);
}

// Round 6
// 567.001 us; speedup vs baseline: 1.5617x; 1.3433x over previous
//
#include <hip/hip_runtime.h>
#include <hip/hip_bf16.h>
#include <stdint.h>

#define T_   8192   // B*S tokens
#define IN_  4096
#define OUT_ 4096
#define GS_  256
#define NG_  16

#define BM 128
#define BN 128
#define BK 128
#define KT (IN_ / BK)   // 32 K-tiles, group = 2 K-tiles

typedef int   v4i __attribute__((ext_vector_type(4)));
typedef float f4  __attribute__((ext_vector_type(4)));

__device__ __forceinline__ void gload16(const void* g, void* l) {
  __builtin_amdgcn_global_load_lds(
      (const __attribute__((address_space(1))) void*)g,
      (__attribute__((address_space(3))) void*)l, 16, 0, 0);
}

// ---------------- per-token dynamic quant ----------------------------------
// Exact divides only for scale/zp; per-element uses x*(1/scale) (rintf slack
// absorbed by the 0.615 absmax threshold; one LSB of q ~ 0.01 in the output).
__global__ __launch_bounds__(256) void quant_kernel(
    const float* __restrict__ x, int8_t* __restrict__ q,
    float* __restrict__ tscale, float* __restrict__ tzp) {
  const int t = blockIdx.x;
  const int tid = threadIdx.x;
  const float* xr = x + (size_t)t * IN_ + tid * 16;
  float vals[16];
  {
    f4 v0 = *(const f4*)(xr);
    f4 v1 = *(const f4*)(xr + 4);
    f4 v2 = *(const f4*)(xr + 8);
    f4 v3 = *(const f4*)(xr + 12);
#pragma unroll
    for (int i = 0; i < 4; ++i) {
      vals[i] = v0[i]; vals[4 + i] = v1[i]; vals[8 + i] = v2[i]; vals[12 + i] = v3[i];
    }
  }
  float mn = 0.f, mx = 0.f;   // ref clamps: min(.,0), max(.,0)
#pragma unroll
  for (int i = 0; i < 16; ++i) { mn = fminf(mn, vals[i]); mx = fmaxf(mx, vals[i]); }
#pragma unroll
  for (int off = 32; off > 0; off >>= 1) {
    mn = fminf(mn, __shfl_xor(mn, off));
    mx = fmaxf(mx, __shfl_xor(mx, off));
  }
  __shared__ float smn[4], smx[4];
  if ((tid & 63) == 0) { smn[tid >> 6] = mn; smx[tid >> 6] = mx; }
  __syncthreads();
  mn = fminf(fminf(smn[0], smn[1]), fminf(smn[2], smn[3]));
  mx = fmaxf(fmaxf(smx[0], smx[1]), fmaxf(smx[2], smx[3]));

  const float eps = 1.1920928955078125e-7f;  // np.finfo(float32).eps
  float scale = fmaxf((mx - mn) / 255.0f, eps);
  float rmn = mn / scale;   // exact divide (zp must be bit-exact)
  float rmx = mx / scale;
  float zp0 = ((-128.0f + rmn) + (127.0f + rmx) > 0.0f) ? (-128.0f - rmn)
                                                        : (127.0f - rmx);
  float zp = fminf(fmaxf(rintf(zp0), -128.0f), 127.0f);
  if (tid == 0) { tscale[t] = scale; tzp[t] = zp; }

  const float inv = 1.0f / scale;  // one exact divide; 16 multiplies below
  v4i packed;
#pragma unroll
  for (int w = 0; w < 4; ++w) {
    int word = 0;
#pragma unroll
    for (int e = 0; e < 4; ++e) {
      float qf = rintf(vals[w * 4 + e] * inv) + zp;
      qf = fminf(fmaxf(qf, -128.0f), 127.0f);
      int qi = (int)qf;
      word |= (qi & 0xff) << (8 * e);
    }
    packed[w] = word;
  }
  *(v4i*)(q + (size_t)t * IN_ + tid * 16) = packed;
}

// ---------------- weight prep: w' = w - z (int8), C1[o] = sum_g s*sum(w') ---
__global__ __launch_bounds__(256) void wprep_kernel(
    const int* __restrict__ w, const float* __restrict__ scales,
    const float* __restrict__ zeros, int8_t* __restrict__ wq,
    float* __restrict__ c1) {
  const int o = blockIdx.x;
  const int tid = threadIdx.x;
  const int g = tid >> 4;  // 16 threads per group of 256 elems
  const int* wr = w + (size_t)o * IN_ + tid * 16;
  const int zi = (int)zeros[o * NG_ + g];
  int ssum = 0;
  v4i packed;
#pragma unroll
  for (int blk = 0; blk < 4; ++blk) {
    v4i ww = *(const v4i*)(wr + blk * 4);
    int word = 0;
#pragma unroll
    for (int e = 0; e < 4; ++e) {
      int wp = ww[e] - zi;   // in [-15,15], fits int8
      ssum += wp;
      word |= (wp & 0xff) << (8 * e);
    }
    packed[blk] = word;
  }
  *(v4i*)(wq + (size_t)o * IN_ + tid * 16) = packed;
  ssum += __shfl_xor(ssum, 1);
  ssum += __shfl_xor(ssum, 2);
  ssum += __shfl_xor(ssum, 4);
  ssum += __shfl_xor(ssum, 8);
  __shared__ float part[NG_];
  if ((tid & 15) == 0) part[g] = scales[o * NG_ + g] * (float)ssum;
  __syncthreads();
  if (tid == 0) {
    float s = 0.f;
#pragma unroll
    for (int i = 0; i < NG_; ++i) s += part[i];
    c1[o] = s;
  }
}

// ---------------- int8 groupwise GEMM: A via LDS, B direct w/ reg-dbuf ------
// Round-5 post-mortem: B-direct was latency-exposed (B consumed in the same
// kt it was loaded; MfmaUtil 10.6%, all pipes idle) and x-major dispatch gave
// co-resident blocks disjoint B panels (L2 thrash).  Fixes, nothing else:
//  1. B register double-buffer: B(kt+1) loaded at top of kt into the spare
//     named register set (loop unrolled x2, no runtime indexing), consumed
//     next iteration -> a full kt body (~1000+ cy) covers L2/L3 latency.
//     The end-of-kt __syncthreads (vmcnt 0) guarantees completion for free.
//  2. Column-major block order (grid x=row-tiles, y=col-tiles): consecutive
//     blocks share C0 -> one 512 KB B-panel per XCD window, L2-resident.
// Pipes (chip-wide): MFMA ~70us, fold-VALU ~70us (co-issues), LDS A-only
// ~46us, L2 B ~62us -- all separate units; r0's LDS saturation (~93us) gone.
__global__ __launch_bounds__(256) void gemm_kernel(
    const int8_t* __restrict__ q, const int8_t* __restrict__ wq,
    const float* __restrict__ scales, const float* __restrict__ tscale,
    const float* __restrict__ tzp, const float* __restrict__ c1,
    float* __restrict__ out) {
  __shared__ int8_t As[2][BM * BK];   // 2 x 16 KB
  __shared__ float sSc[NG_ * BN];     // 8 KB   (40 KB total)

  const int tid = threadIdx.x;
  const int lane = tid & 63;
  const int wid = tid >> 6;
  const int R0 = blockIdx.x * BM;   // x = row tiles (fast-varying)
  const int C0 = blockIdx.y * BN;   // y = col tiles -> co-resident share C0

  // stage this block's scales: sSc[g][col_local]
#pragma unroll
  for (int e = 0; e < 8; ++e) {
    int idx = tid + e * 256;
    int oc = idx >> 4, g = idx & 15;
    sSc[g * BN + oc] = scales[(size_t)(C0 + oc) * NG_ + g];
  }

  // A staging: thread covers 16 B; row = tid>>3 (+32 per i), phys chunk tid&7
  const int rA = tid >> 3;                       // 0..31
  const int cswz = ((tid & 7) ^ (rA & 7)) * 16;  // swizzled global column
  const int8_t* gA = q + (size_t)(R0 + rA) * IN_ + cswz;

  const int wm = (wid >> 1) * 64;
  const int wn = (wid & 1) * 64;
  const int lm = lane & 15;
  const int quad = lane >> 4;
  // A fragment read offsets: logical chunk (ks*4+quad) ^ (lm&7)
  const int o0 = ((quad ^ (lm & 7)) * 16);       // ks=0
  const int aRow = (wm + lm) * BK;

  // B fragment base: row C0+wn+lm (+16j), k-bytes kt*128 + ks*64 + quad*16
  const int8_t* bBase = wq + (size_t)(C0 + wn + lm) * IN_ + quad * 16;

  v4i acci[4][4];
  float accf[4][4][4];
#pragma unroll
  for (int i = 0; i < 4; ++i)
#pragma unroll
    for (int j = 0; j < 4; ++j) {
      acci[i][j] = (v4i){0, 0, 0, 0};
#pragma unroll
      for (int r = 0; r < 4; ++r) accf[i][j][r] = 0.f;
    }

  // one body = one kt: prefetch B(kt+1)->BN*, A(kt+1)->ANEXT; compute from
  // BC*/ACUR; optional group fold; sync (drains both prefetches).
#define GEMM_BODY(KT_I, BC0, BC1, BNX0, BNX1, ACUR, ANEXT, DO_FOLD)           \
  {                                                                           \
    if ((KT_I) + 1 < KT) {                                                    \
      const int8_t* bk = bBase + (size_t)((KT_I) + 1) * BK;                   \
      _Pragma("unroll")                                                       \
      for (int j = 0; j < 4; ++j) {                                           \
        BNX0[j] = *(const v4i*)(bk + (size_t)j * (16 * IN_));                 \
        BNX1[j] = *(const v4i*)(bk + (size_t)j * (16 * IN_) + 64);            \
      }                                                                       \
      const size_t koff = (size_t)((KT_I) + 1) * BK;                          \
      _Pragma("unroll")                                                       \
      for (int i = 0; i < 4; ++i)                                             \
        gload16(gA + koff + (size_t)(i * 32) * IN_,                           \
                &(ANEXT)[i * 4096 + tid * 16]);                               \
    }                                                                         \
    {                                                                         \
      v4i af[4];                                                              \
      _Pragma("unroll")                                                       \
      for (int i = 0; i < 4; ++i)                                             \
        af[i] = *(const v4i*)&(ACUR)[aRow + i * (16 * BK) + o0];              \
      _Pragma("unroll")                                                       \
      for (int i = 0; i < 4; ++i)                                             \
        _Pragma("unroll")                                                     \
        for (int j = 0; j < 4; ++j)                                           \
          acci[i][j] = __builtin_amdgcn_mfma_i32_16x16x64_i8(                 \
              af[i], BC0[j], acci[i][j], 0, 0, 0);                            \
    }                                                                         \
    {                                                                         \
      const int co = o0 ^ 64;                                                 \
      v4i af[4];                                                              \
      _Pragma("unroll")                                                       \
      for (int i = 0; i < 4; ++i)                                             \
        af[i] = *(const v4i*)&(ACUR)[aRow + i * (16 * BK) + co];              \
      _Pragma("unroll")                                                       \
      for (int i = 0; i < 4; ++i)                                             \
        _Pragma("unroll")                                                     \
        for (int j = 0; j < 4; ++j)                                           \
          acci[i][j] = __builtin_amdgcn_mfma_i32_16x16x64_i8(                 \
              af[i], BC1[j], acci[i][j], 0, 0, 0);                            \
    }                                                                         \
    if (DO_FOLD) {                                                            \
      const int g = (KT_I) >> 1;                                              \
      float sj[4];                                                            \
      _Pragma("unroll")                                                       \
      for (int j = 0; j < 4; ++j) sj[j] = sSc[g * BN + wn + j * 16 + lm];     \
      _Pragma("unroll")                                                       \
      for (int i = 0; i < 4; ++i)                                             \
        _Pragma("unroll")                                                     \
        for (int j = 0; j < 4; ++j) {                                         \
          _Pragma("unroll")                                                   \
          for (int r = 0; r < 4; ++r)                                         \
            accf[i][j][r] += sj[j] * (float)acci[i][j][r];                    \
          acci[i][j] = (v4i){0, 0, 0, 0};                                     \
        }                                                                     \
    }                                                                         \
    __syncthreads();                                                          \
  }

  // prologue: B(0) -> bfA regs, A(0) -> As[0]
  v4i bfA0[4], bfA1[4], bfB0[4], bfB1[4];
#pragma unroll
  for (int j = 0; j < 4; ++j) {
    bfA0[j] = *(const v4i*)(bBase + (size_t)j * (16 * IN_));
    bfA1[j] = *(const v4i*)(bBase + (size_t)j * (16 * IN_) + 64);
  }
#pragma unroll
  for (int i = 0; i < 4; ++i)
    gload16(gA + (size_t)(i * 32) * IN_, &As[0][i * 4096 + tid * 16]);
  __syncthreads();   // tile 0 + sSc resident (B(0) already in regs)

  for (int kt = 0; kt < KT; kt += 2) {
    GEMM_BODY(kt,     bfA0, bfA1, bfB0, bfB1, As[0], As[1], false)
    GEMM_BODY(kt + 1, bfB0, bfB1, bfA0, bfA1, As[1], As[0], true)
  }
#undef GEMM_BODY

  // epilogue: out = scale_t * (accf - zp_t * C1[o])
  float cj[4];
#pragma unroll
  for (int j = 0; j < 4; ++j) cj[j] = c1[C0 + wn + j * 16 + lm];
#pragma unroll
  for (int i = 0; i < 4; ++i) {
#pragma unroll
    for (int r = 0; r < 4; ++r) {
      const int row = R0 + wm + i * 16 + quad * 4 + r;
      const float tsc = tscale[row];
      const float tz = tzp[row];
#pragma unroll
      for (int j = 0; j < 4; ++j) {
        const int col = C0 + wn + j * 16 + lm;
        out[(size_t)row * OUT_ + col] = tsc * (accf[i][j][r] - tz * cj[j]);
      }
    }
  }
}

extern "C" void kernel_launch(void* const* d_in, const int* in_sizes, int n_in,
                              void* d_out, int out_size, void* d_ws, size_t ws_size,
                              hipStream_t stream) {
  const float* x = (const float*)d_in[0];
  const int* w = (const int*)d_in[1];       // int inputs materialized as int32
  const float* scales = (const float*)d_in[2];
  const float* zeros = (const float*)d_in[3];
  // d_in[4] = group_size scalar (256), baked in at compile time

  uint8_t* ws = (uint8_t*)d_ws;
  int8_t* q = (int8_t*)ws;                                  // 33,554,432 B
  int8_t* wq = (int8_t*)(ws + 33554432);                    // 16,777,216 B
  float* tscale = (float*)(ws + 33554432 + 16777216);       // 32 KB
  float* tzp = (float*)(ws + 33554432 + 16777216 + 32768);  // 32 KB
  float* c1 = (float*)(ws + 33554432 + 16777216 + 65536);   // 16 KB
  float* out = (float*)d_out;

  hipLaunchKernelGGL(quant_kernel, dim3(T_), dim3(256), 0, stream, x, q, tscale, tzp);
  hipLaunchKernelGGL(wprep_kernel, dim3(OUT_), dim3(256), 0, stream, w, scales, zeros, wq, c1);
  // grid: x = row tiles (fast), y = col tiles -> co-resident blocks share B
  hipLaunchKernelGGL(gemm_kernel, dim3(T_ / BM, OUT_ / BN), dim3(256), 0, stream,
                     q, wq, scales, tscale, tzp, c1, out);
}